// Round 12
// baseline (8547.543 us; speedup 1.0000x reference)
//
#include <hip/hip_runtime.h>
#include <hip/hip_bf16.h>
#include <math.h>

// ConsciousnessStream: B=32, T=2048, E=1024, S=24
// out = [stream (32*24*1024 f32)] [trace (32*2048*1024 f32)]

typedef __attribute__((ext_vector_type(4))) float f32x4;
typedef __attribute__((ext_vector_type(2))) float f32x2;
typedef __attribute__((ext_vector_type(8))) short bf16x8;

__device__ __forceinline__ ushort f2bf(float f) {
  unsigned int x = __float_as_uint(f);
  x += 0x7fffu + ((x >> 16) & 1u);   // RNE (finite data, no NaN handling)
  return (ushort)(x >> 16);
}
__device__ __forceinline__ float bf2f(ushort u) {
  return __uint_as_float(((unsigned int)u) << 16);
}
__device__ __forceinline__ float sigf(float x) {
  return 1.0f / (1.0f + __expf(-x));
}
__device__ __forceinline__ void gload_lds16(const void* g, void* l) {
  __builtin_amdgcn_global_load_lds(
      (const __attribute__((address_space(1))) unsigned int*)g,
      (__attribute__((address_space(3))) unsigned int*)l, 16, 0, 0);
}

// ---------------------------------------------------------------- converts
__global__ __launch_bounds__(256) void f32_to_bf16_k(const float* __restrict__ in,
                                                     ushort* __restrict__ out, int n) {
  int i = (blockIdx.x * 256 + threadIdx.x) * 8;
  if (i >= n) return;
  float4 a = *(const float4*)(in + i);
  float4 c = *(const float4*)(in + i + 4);
  union { ushort u[8]; uint4 v; } p;
  p.u[0]=f2bf(a.x); p.u[1]=f2bf(a.y); p.u[2]=f2bf(a.z); p.u[3]=f2bf(a.w);
  p.u[4]=f2bf(c.x); p.u[5]=f2bf(c.y); p.u[6]=f2bf(c.z); p.u[7]=f2bf(c.w);
  *(uint4*)(out + i) = p.v;
}

// ------------------------------------------------- bf16 GEMM, Bt = [N][K]
// EPI=0: C = bf16(acc + bias[col]) stored at GI[(t*32+b)*3072+col], m=b*2048+t
// EPI=1: C = bf16(gelu(acc + bias[col])) stored row-major [m][256]
template<int EPI>
__global__ __launch_bounds__(256) void gemm_bt(
    const ushort* __restrict__ A, const ushort* __restrict__ Bt,
    const float* __restrict__ bias, ushort* __restrict__ C,
    int M, int N, int K)
{
  __shared__ ushort lA[128 * 32];
  __shared__ ushort lB[128 * 32];
  const int tid = threadIdx.x;
  const int lane = tid & 63, wid = tid >> 6;
  const int tiles_n = N >> 7;
  const int tm = blockIdx.x / tiles_n, tn = blockIdx.x % tiles_n;
  const int wr = wid >> 1, wc = wid & 1;

  const f32x4 zero = {0.f, 0.f, 0.f, 0.f};
  f32x4 acc[4][4];
#pragma unroll
  for (int i = 0; i < 4; ++i)
#pragma unroll
    for (int n = 0; n < 4; ++n) acc[i][n] = zero;

  const ushort* gA = A + (size_t)tm * 128 * K;
  const ushort* gB = Bt + (size_t)tn * 128 * K;
  const int k0 = (lane >> 4) * 8;

  for (int kt = 0; kt < K; kt += 32) {
    __syncthreads();
#pragma unroll
    for (int i = 0; i < 2; ++i) {
      int chunk = i * 256 + tid;          // 512 16B-chunks per 128x32 tile
      int rr = chunk >> 2, cc = chunk & 3;
      gload_lds16(gA + (size_t)rr * K + kt + cc * 8, lA + chunk * 8);
      gload_lds16(gB + (size_t)rr * K + kt + cc * 8, lB + chunk * 8);
    }
    __syncthreads();
    bf16x8 af[4], bfv[4];
#pragma unroll
    for (int i = 0; i < 4; ++i)
      af[i] = *(const bf16x8*)(lA + (wr * 64 + i * 16 + (lane & 15)) * 32 + k0);
#pragma unroll
    for (int n = 0; n < 4; ++n)
      bfv[n] = *(const bf16x8*)(lB + (wc * 64 + n * 16 + (lane & 15)) * 32 + k0);
#pragma unroll
    for (int i = 0; i < 4; ++i)
#pragma unroll
      for (int n = 0; n < 4; ++n)
        acc[i][n] = __builtin_amdgcn_mfma_f32_16x16x32_bf16(af[i], bfv[n], acc[i][n], 0, 0, 0);
  }

#pragma unroll
  for (int i = 0; i < 4; ++i) {
#pragma unroll
    for (int n = 0; n < 4; ++n) {
#pragma unroll
      for (int j = 0; j < 4; ++j) {
        int m = tm * 128 + wr * 64 + i * 16 + (lane >> 4) * 4 + j;
        int col = tn * 128 + wc * 64 + n * 16 + (lane & 15);
        float v = acc[i][n][j] + bias[col];
        if (EPI == 0) {
          int tt = m & 2047, bb = m >> 11;
          C[(size_t)(tt * 32 + bb) * 3072 + col] = f2bf(v);
        } else {
          float gl = 0.5f * v * (1.0f + erff(v * 0.70710678f));
          C[(size_t)m * 256 + col] = f2bf(gl);
        }
      }
    }
  }
}

// -------------------------------------------- gate reduce: g = sig(GH1.w2+b2)
__global__ __launch_bounds__(256) void gate_reduce(
    const ushort* __restrict__ GH1, const float* __restrict__ w2,
    const float* __restrict__ b2, float* __restrict__ G)
{
  int row = blockIdx.x * 4 + (threadIdx.x >> 6);  // m = b*2048 + t
  int lane = threadIdx.x & 63;
  const ushort* p = GH1 + (size_t)row * 256 + lane * 4;
  ushort4 h4 = *(const ushort4*)p;
  float4 w4 = *(const float4*)(w2 + lane * 4);
  float s = bf2f(h4.x) * w4.x + bf2f(h4.y) * w4.y + bf2f(h4.z) * w4.z + bf2f(h4.w) * w4.w;
#pragma unroll
  for (int o = 32; o > 0; o >>= 1) s += __shfl_down(s, o);
  if (lane == 0) {
    G[(row & 2047) * 32 + (row >> 11)] = sigf(s + b2[0]);
  }
}

// ------------------------------------------------------------------- init
// Tagged h ring: 2 bufs x 8 groups x 2048 words x 8B.
// word = {lo32: 2xbf16 data, hi32: tag}. buf0 <- h0 with tag 0;
// buf1 <- tag 0xFFFFFFFF (clears stale tags from previous graph replays).
__global__ __launch_bounds__(256) void init_scan(const float* __restrict__ prev,
                                                 ushort* __restrict__ hb)
{
  int gid = blockIdx.x * 256 + threadIdx.x;   // grid 64*256 = 16384 words
  if (gid >= 16384) return;
  int Gp = gid >> 11, idx = gid & 2047;
  int b = idx >> 9, p = idx & 511;
  int brow = Gp * 4 + b;
  const float* src = prev + ((size_t)brow * 24 + 23) * 1024 + p * 2;
  unsigned int data = (unsigned int)f2bf(src[0]) | ((unsigned int)f2bf(src[1]) << 16);
  char* base = (char*)hb;
  *(unsigned long long*)(base + (size_t)Gp * 16384 + (size_t)idx * 8) =
      (unsigned long long)data;                                   // tag 0
  *(unsigned long long*)(base + 131072 + (size_t)Gp * 16384 + (size_t)idx * 8) =
      0xFFFFFFFF00000000ULL;                                      // invalid tag
}

// ------------------------------------------------------- persistent scan
// BATCH-GROUP decomposition: 8 independent groups x 32 WGs (grid 256, 1/CU).
// Group Gp owns batch rows 4Gp..4Gp+3; WG c owns h-outputs e in
// [c*32, c*32+32) with the matching 96 w_hh rows in VGPRs/AGPRs.
// TAGGED-WORD BROADCAST: h published as 8B words {data, tag=t+1} via
// fire-and-forget sc0sc1 stores; consumers retry-load until tags match.
// ROLE SPLIT (R11 post-mortem): staging = waves 1-4 (tid 64..320), combine =
// wave 0 -- combine/publish/trace overlap the other waves' retry loads.
// 2 barriers/step (B3 removed -- redundant by tag causality: staging
// completes only after ALL combines published, which follows ghx reads).
__global__ __launch_bounds__(384, 2) void scan_kernel(
    const ushort* __restrict__ GI, const float* __restrict__ G,
    const float* __restrict__ w_hh, const float* __restrict__ b_hh,
    ushort* __restrict__ hb, float* __restrict__ out)
{
  __shared__ ushort hl[16 * 1024];   // staged h, M=16 rows (rows 4-15 zero), swizzled
  __shared__ float ghx[4 * 96];      // gh exchange [b][gate*32+e_local]
  const int tid = threadIdx.x;
  const int wgid = blockIdx.x;       // 0..255
  const int Gp = wgid >> 5;          // group 0..7
  const int c  = wgid & 31;          // CU within group
  const int wid = tid >> 6, lane = tid & 63;
  char* hbb = (char*)hb;

  const int gateW = wid >> 1;            // 0..2 (r,z,n)
  const int ehW = (wid & 1) * 16;        // e sub-tile within the 32

  // one-time: this wave's 32 w_hh B-fragments -> registers (bf16).
  bf16x8 bfr[32];
  {
    const float* wsrc = w_hh
        + ((size_t)(gateW * 1024 + c * 32 + ehW + (lane & 15))) * 1024
        + (lane >> 4) * 8;
#pragma unroll
    for (int kk = 0; kk < 32; ++kk) {
      float4 f0 = *(const float4*)(wsrc + kk * 32);
      float4 f1 = *(const float4*)(wsrc + kk * 32 + 4);
      union { ushort u[8]; bf16x8 v; } p;
      p.u[0]=f2bf(f0.x); p.u[1]=f2bf(f0.y); p.u[2]=f2bf(f0.z); p.u[3]=f2bf(f0.w);
      p.u[4]=f2bf(f1.x); p.u[5]=f2bf(f1.y); p.u[6]=f2bf(f1.z); p.u[7]=f2bf(f1.w);
      bfr[kk] = p.v;
    }
  }

  // zero pad rows 4..15 of the h stage (written once, swizzled layout)
  for (int idx = tid; idx < 1536; idx += 384) {
    int r = 4 + (idx >> 7), cc = idx & 127;
    int byte = (r * 2048 + cc * 16) ^ ((r & 7) << 4);
    uint4 z = {0u, 0u, 0u, 0u};
    *(uint4*)((char*)hl + byte) = z;
  }

  // A-frag read constants
  const int arow = lane & 15;            // batch row (0..3 valid)
  const int k0b = (lane >> 4) * 16;
  const int abase = arow * 2048, aswz = (arow & 7) << 4;
  const char* hlc = (const char*)hl;

  // combine-thread constants (tid<64): b=tid>>4 (4 rows), ep=tid&15 (e-pairs)
  const int b = tid >> 4;
  const int ep = tid & 15;
  const int brow = Gp * 4 + b;           // global batch row
  const int e2 = c * 32 + ep * 2;        // global e (pair base)
  float bhr0=0, bhr1=0, bhz0=0, bhz1=0, bhn0=0, bhn1=0;
  float h0r = 0.f, h1r = 0.f;            // own h pair in f32 registers
  unsigned int gir = 0, giz = 0, gin = 0; float gval = 0.f;
  if (tid < 64) {
    bhr0 = b_hh[e2];        bhr1 = b_hh[e2 + 1];
    bhz0 = b_hh[1024 + e2]; bhz1 = b_hh[1025 + e2];
    bhn0 = b_hh[2048 + e2]; bhn1 = b_hh[2049 + e2];
    // own h0 pair from the tagged buf0 (plain load; init ran on this stream)
    unsigned int v = *(const unsigned int*)(hbb + (size_t)Gp * 16384
                                            + (size_t)(b * 512 + c * 16 + ep) * 8);
    h0r = bf2f((ushort)(v & 0xffff)); h1r = bf2f((ushort)(v >> 16));
    const ushort* gp = GI + (size_t)brow * 3072 + e2;   // step-0 prefetch
    gir = *(const unsigned int*)(gp);
    giz = *(const unsigned int*)(gp + 1024);
    gin = *(const unsigned int*)(gp + 2048);
    gval = G[brow];
  }

  __syncthreads();

  for (int t = 0; t < 2048; ++t) {
    // stage h_t (waves 1-4): retry-load 4x16B tagged words until tags == t,
    // then extract data dwords -> LDS swizzled. 256 staging threads cover 16KB.
    if (tid >= 64 && tid < 320) {
      const int stid = tid - 64;
      const char* base = hbb + (size_t)(t & 1) * 131072 + (size_t)Gp * 16384
                         + (size_t)stid * 64;
      uint4 v0, v1, v2, v3;
      unsigned int tg = (unsigned int)t;
      for (;;) {
        asm volatile("global_load_dwordx4 %0, %1, off sc0 sc1"
                     : "=&v"(v0) : "v"(base) : "memory");
        asm volatile("global_load_dwordx4 %0, %1, off sc0 sc1"
                     : "=&v"(v1) : "v"(base + 16) : "memory");
        asm volatile("global_load_dwordx4 %0, %1, off sc0 sc1"
                     : "=&v"(v2) : "v"(base + 32) : "memory");
        asm volatile("global_load_dwordx4 %0, %1, off sc0 sc1"
                     : "=&v"(v3) : "v"(base + 48) : "memory");
        asm volatile("s_waitcnt vmcnt(0)" ::: "memory");
        if (v0.y == tg && v0.w == tg && v1.y == tg && v1.w == tg &&
            v2.y == tg && v2.w == tg && v3.y == tg && v3.w == tg) break;
        __builtin_amdgcn_s_sleep(1);
      }
      __builtin_amdgcn_sched_barrier(0);
      int r = stid >> 6, colb = (stid & 63) * 32, swz = (r & 7) << 4;
      uint4 da; da.x = v0.x; da.y = v0.z; da.z = v1.x; da.w = v1.z;
      uint4 db; db.x = v2.x; db.y = v2.z; db.z = v3.x; db.w = v3.z;
      *(uint4*)((char*)hl + ((r * 2048 + colb) ^ swz)) = da;
      *(uint4*)((char*)hl + ((r * 2048 + colb + 16) ^ swz)) = db;
    }
    asm volatile("s_waitcnt lgkmcnt(0)\n\ts_barrier" ::: "memory");   // B1 (LDS)
    __builtin_amdgcn_sched_barrier(0);

    // gh tile: M=4(in 16) x N=16 x K=1024 per wave; 4 indep acc chains
    f32x4 acc0 = {0.f,0.f,0.f,0.f}, acc1 = {0.f,0.f,0.f,0.f};
    f32x4 acc2 = {0.f,0.f,0.f,0.f}, acc3 = {0.f,0.f,0.f,0.f};
#pragma unroll
    for (int kk = 0; kk < 32; kk += 4) {
      int ka = kk * 64 + k0b;
      bf16x8 a0 = *(const bf16x8*)(hlc + abase + ((ka) ^ aswz));
      bf16x8 a1 = *(const bf16x8*)(hlc + abase + ((ka + 64) ^ aswz));
      bf16x8 a2 = *(const bf16x8*)(hlc + abase + ((ka + 128) ^ aswz));
      bf16x8 a3 = *(const bf16x8*)(hlc + abase + ((ka + 192) ^ aswz));
      acc0 = __builtin_amdgcn_mfma_f32_16x16x32_bf16(a0, bfr[kk],     acc0, 0, 0, 0);
      acc1 = __builtin_amdgcn_mfma_f32_16x16x32_bf16(a1, bfr[kk + 1], acc1, 0, 0, 0);
      acc2 = __builtin_amdgcn_mfma_f32_16x16x32_bf16(a2, bfr[kk + 2], acc2, 0, 0, 0);
      acc3 = __builtin_amdgcn_mfma_f32_16x16x32_bf16(a3, bfr[kk + 3], acc3, 0, 0, 0);
    }
    // D rows 0-3 (the real batch rows) live in lanes 0-15, reg j = row
    if (lane < 16) {
      f32x4 s = (acc0 + acc1) + (acc2 + acc3);
#pragma unroll
      for (int j = 0; j < 4; ++j)
        ghx[j * 96 + gateW * 32 + ehW + lane] = s[j];
    }
    asm volatile("s_waitcnt lgkmcnt(0)\n\ts_barrier" ::: "memory");   // B2 (LDS)
    __builtin_amdgcn_sched_barrier(0);

    // local combine (wave 0); publish h_{t+1} as tagged words, then trace +
    // next-step prefetch -- all overlapped with waves 1-4's staging retries.
    if (tid < 64) {
      float hr0v = ghx[b * 96 + ep * 2],      hr1v = ghx[b * 96 + ep * 2 + 1];
      float hz0v = ghx[b * 96 + 32 + ep * 2], hz1v = ghx[b * 96 + 33 + ep * 2];
      float hn0v = ghx[b * 96 + 64 + ep * 2], hn1v = ghx[b * 96 + 65 + ep * 2];
      float r0 = sigf(bf2f((ushort)(gir & 0xffff)) + hr0v + bhr0);
      float r1 = sigf(bf2f((ushort)(gir >> 16))    + hr1v + bhr1);
      float z0 = sigf(bf2f((ushort)(giz & 0xffff)) + hz0v + bhz0);
      float z1 = sigf(bf2f((ushort)(giz >> 16))    + hz1v + bhz1);
      float n0 = 2.f * sigf(2.f * (bf2f((ushort)(gin & 0xffff)) + r0 * (hn0v + bhn0))) - 1.f;
      float n1 = 2.f * sigf(2.f * (bf2f((ushort)(gin >> 16))    + r1 * (hn1v + bhn1))) - 1.f;
      float nw0 = (1.f - z0) * n0 + z0 * h0r;
      float nw1 = (1.f - z1) * n1 + z1 * h1r;
      float u0 = gval * nw0 + (1.f - gval) * h0r;
      float u1 = gval * nw1 + (1.f - gval) * h1r;
      h0r = u0; h1r = u1;
      unsigned int hp = (unsigned int)f2bf(u0) | ((unsigned int)f2bf(u1) << 16);
      unsigned long long wd = ((unsigned long long)(unsigned int)(t + 1) << 32) | hp;
      char* haddr = hbb + (size_t)((t + 1) & 1) * 131072 + (size_t)Gp * 16384
                    + (size_t)(b * 512 + c * 16 + ep) * 8;
      asm volatile("global_store_dwordx2 %0, %1, off sc0 sc1"
                   :: "v"(haddr), "v"(wd) : "memory");
      // off the publication path: trace/stream + next-step prefetch
      f32x2 uv; uv.x = u0; uv.y = u1;
      __builtin_nontemporal_store(uv,
          (f32x2*)(out + 786432 + ((size_t)brow * 2048 + t) * 1024 + e2));     // trace
      if (t >= 2024)
        __builtin_nontemporal_store(uv,
            (f32x2*)(out + ((size_t)brow * 24 + (t - 2024)) * 1024 + e2));     // stream
      int tn1 = t < 2047 ? t + 1 : 2047;
      const ushort* gp = GI + ((size_t)tn1 * 32 + brow) * 3072 + e2;
      gir = *(const unsigned int*)(gp);
      giz = *(const unsigned int*)(gp + 1024);
      gin = *(const unsigned int*)(gp + 2048);
      gval = G[tn1 * 32 + brow];
    }
    // no B3: tag causality orders ghx/hl reuse (see header comment)
  }
}

// ------------------------------------------------------------------ launch
extern "C" void kernel_launch(void* const* d_in, const int* in_sizes, int n_in,
                              void* d_out, int out_size, void* d_ws, size_t ws_size,
                              hipStream_t stream) {
  const float* x    = (const float*)d_in[0];
  const float* prev = (const float*)d_in[1];
  const float* gw1  = (const float*)d_in[2];
  const float* gb1  = (const float*)d_in[3];
  const float* gw2  = (const float*)d_in[4];
  const float* gb2  = (const float*)d_in[5];
  const float* wih  = (const float*)d_in[6];
  const float* whh  = (const float*)d_in[7];
  const float* bih  = (const float*)d_in[8];
  const float* bhh  = (const float*)d_in[9];
  float* out = (float*)d_out;

  char* ws = (char*)d_ws;
  ushort* xb    = (ushort*)(ws);                       // 134,217,728 B
  ushort* wbih  = (ushort*)(ws + 134217728);           //   6,291,456 B
  ushort* wb1   = (ushort*)(ws + 140509184);           //     524,288 B
  ushort* GI    = (ushort*)(ws + 141033472);           // 402,653,184 B
  ushort* GH1   = (ushort*)(ws + 543686656);           //  33,554,432 B
  float*  Gg    = (float*) (ws + 577241088);           //     262,144 B
  ushort* hb    = (ushort*)(ws + 577503232);           //     262,144 B (2 tagged bufs)
  // total 577,765,376 B (~551 MiB) of d_ws

  f32_to_bf16_k<<<32768, 256, 0, stream>>>(x, xb, 67108864);
  f32_to_bf16_k<<<1536, 256, 0, stream>>>(wih, wbih, 3145728);
  f32_to_bf16_k<<<128, 256, 0, stream>>>(gw1, wb1, 262144);
  gemm_bt<0><<<12288, 256, 0, stream>>>(xb, wbih, bih, GI, 65536, 3072, 1024);
  gemm_bt<1><<<1024, 256, 0, stream>>>(xb, wb1, gb1, GH1, 65536, 256, 1024);
  gate_reduce<<<16384, 256, 0, stream>>>(GH1, gw2, gb2, Gg);
  init_scan<<<64, 256, 0, stream>>>(prev, hb);
  scan_kernel<<<256, 384, 0, stream>>>(GI, Gg, whh, bhh, hb, out);
}

// Round 13
// 6497.418 us; speedup vs baseline: 1.3155x; 1.3155x over previous
//
#include <hip/hip_runtime.h>
#include <hip/hip_bf16.h>
#include <math.h>

// ConsciousnessStream: B=32, T=2048, E=1024, S=24
// out = [stream (32*24*1024 f32)] [trace (32*2048*1024 f32)]

typedef __attribute__((ext_vector_type(4))) float f32x4;
typedef __attribute__((ext_vector_type(2))) float f32x2;
typedef __attribute__((ext_vector_type(8))) short bf16x8;

__device__ __forceinline__ ushort f2bf(float f) {
  unsigned int x = __float_as_uint(f);
  x += 0x7fffu + ((x >> 16) & 1u);   // RNE (finite data, no NaN handling)
  return (ushort)(x >> 16);
}
__device__ __forceinline__ float bf2f(ushort u) {
  return __uint_as_float(((unsigned int)u) << 16);
}
__device__ __forceinline__ float sigf(float x) {
  return 1.0f / (1.0f + __expf(-x));
}
__device__ __forceinline__ void gload_lds16(const void* g, void* l) {
  __builtin_amdgcn_global_load_lds(
      (const __attribute__((address_space(1))) unsigned int*)g,
      (__attribute__((address_space(3))) unsigned int*)l, 16, 0, 0);
}

// ---------------------------------------------------------------- converts
__global__ __launch_bounds__(256) void f32_to_bf16_k(const float* __restrict__ in,
                                                     ushort* __restrict__ out, int n) {
  int i = (blockIdx.x * 256 + threadIdx.x) * 8;
  if (i >= n) return;
  float4 a = *(const float4*)(in + i);
  float4 c = *(const float4*)(in + i + 4);
  union { ushort u[8]; uint4 v; } p;
  p.u[0]=f2bf(a.x); p.u[1]=f2bf(a.y); p.u[2]=f2bf(a.z); p.u[3]=f2bf(a.w);
  p.u[4]=f2bf(c.x); p.u[5]=f2bf(c.y); p.u[6]=f2bf(c.z); p.u[7]=f2bf(c.w);
  *(uint4*)(out + i) = p.v;
}

// ------------------------------------------------- bf16 GEMM, Bt = [N][K]
// EPI=0: C = bf16(acc + bias[col]) stored at GI[(t*32+b)*3072+col], m=b*2048+t
// EPI=1: C = bf16(gelu(acc + bias[col])) stored row-major [m][256]
template<int EPI>
__global__ __launch_bounds__(256) void gemm_bt(
    const ushort* __restrict__ A, const ushort* __restrict__ Bt,
    const float* __restrict__ bias, ushort* __restrict__ C,
    int M, int N, int K)
{
  __shared__ ushort lA[128 * 32];
  __shared__ ushort lB[128 * 32];
  const int tid = threadIdx.x;
  const int lane = tid & 63, wid = tid >> 6;
  const int tiles_n = N >> 7;
  const int tm = blockIdx.x / tiles_n, tn = blockIdx.x % tiles_n;
  const int wr = wid >> 1, wc = wid & 1;

  const f32x4 zero = {0.f, 0.f, 0.f, 0.f};
  f32x4 acc[4][4];
#pragma unroll
  for (int i = 0; i < 4; ++i)
#pragma unroll
    for (int n = 0; n < 4; ++n) acc[i][n] = zero;

  const ushort* gA = A + (size_t)tm * 128 * K;
  const ushort* gB = Bt + (size_t)tn * 128 * K;
  const int k0 = (lane >> 4) * 8;

  for (int kt = 0; kt < K; kt += 32) {
    __syncthreads();
#pragma unroll
    for (int i = 0; i < 2; ++i) {
      int chunk = i * 256 + tid;          // 512 16B-chunks per 128x32 tile
      int rr = chunk >> 2, cc = chunk & 3;
      gload_lds16(gA + (size_t)rr * K + kt + cc * 8, lA + chunk * 8);
      gload_lds16(gB + (size_t)rr * K + kt + cc * 8, lB + chunk * 8);
    }
    __syncthreads();
    bf16x8 af[4], bfv[4];
#pragma unroll
    for (int i = 0; i < 4; ++i)
      af[i] = *(const bf16x8*)(lA + (wr * 64 + i * 16 + (lane & 15)) * 32 + k0);
#pragma unroll
    for (int n = 0; n < 4; ++n)
      bfv[n] = *(const bf16x8*)(lB + (wc * 64 + n * 16 + (lane & 15)) * 32 + k0);
#pragma unroll
    for (int i = 0; i < 4; ++i)
#pragma unroll
      for (int n = 0; n < 4; ++n)
        acc[i][n] = __builtin_amdgcn_mfma_f32_16x16x32_bf16(af[i], bfv[n], acc[i][n], 0, 0, 0);
  }

#pragma unroll
  for (int i = 0; i < 4; ++i) {
#pragma unroll
    for (int n = 0; n < 4; ++n) {
#pragma unroll
      for (int j = 0; j < 4; ++j) {
        int m = tm * 128 + wr * 64 + i * 16 + (lane >> 4) * 4 + j;
        int col = tn * 128 + wc * 64 + n * 16 + (lane & 15);
        float v = acc[i][n][j] + bias[col];
        if (EPI == 0) {
          int tt = m & 2047, bb = m >> 11;
          C[(size_t)(tt * 32 + bb) * 3072 + col] = f2bf(v);
        } else {
          float gl = 0.5f * v * (1.0f + erff(v * 0.70710678f));
          C[(size_t)m * 256 + col] = f2bf(gl);
        }
      }
    }
  }
}

// -------------------------------------------- gate reduce: g = sig(GH1.w2+b2)
__global__ __launch_bounds__(256) void gate_reduce(
    const ushort* __restrict__ GH1, const float* __restrict__ w2,
    const float* __restrict__ b2, float* __restrict__ G)
{
  int row = blockIdx.x * 4 + (threadIdx.x >> 6);  // m = b*2048 + t
  int lane = threadIdx.x & 63;
  const ushort* p = GH1 + (size_t)row * 256 + lane * 4;
  ushort4 h4 = *(const ushort4*)p;
  float4 w4 = *(const float4*)(w2 + lane * 4);
  float s = bf2f(h4.x) * w4.x + bf2f(h4.y) * w4.y + bf2f(h4.z) * w4.z + bf2f(h4.w) * w4.w;
#pragma unroll
  for (int o = 32; o > 0; o >>= 1) s += __shfl_down(s, o);
  if (lane == 0) {
    G[(row & 2047) * 32 + (row >> 11)] = sigf(s + b2[0]);
  }
}

// ------------------------------------------------------------------- init
// Tagged h ring: 2 bufs x 8 groups x 2048 words x 8B.
// word = {lo32: 2xbf16 data, hi32: tag}. buf0 <- h0 with tag 0;
// buf1 <- tag 0xFFFFFFFF (clears stale tags from previous graph replays).
__global__ __launch_bounds__(256) void init_scan(const float* __restrict__ prev,
                                                 ushort* __restrict__ hb)
{
  int gid = blockIdx.x * 256 + threadIdx.x;   // grid 64*256 = 16384 words
  if (gid >= 16384) return;
  int Gp = gid >> 11, idx = gid & 2047;
  int b = idx >> 9, p = idx & 511;
  int brow = Gp * 4 + b;
  const float* src = prev + ((size_t)brow * 24 + 23) * 1024 + p * 2;
  unsigned int data = (unsigned int)f2bf(src[0]) | ((unsigned int)f2bf(src[1]) << 16);
  char* base = (char*)hb;
  *(unsigned long long*)(base + (size_t)Gp * 16384 + (size_t)idx * 8) =
      (unsigned long long)data;                                   // tag 0
  *(unsigned long long*)(base + 131072 + (size_t)Gp * 16384 + (size_t)idx * 8) =
      0xFFFFFFFF00000000ULL;                                      // invalid tag
}

// ------------------------------------------------------- persistent scan
// BATCH-GROUP decomposition: 8 independent groups x 32 WGs (grid 256, 1/CU).
// Group Gp owns batch rows 4Gp..4Gp+3; WG c owns h-outputs e in
// [c*32, c*32+32) with the matching 96 w_hh rows in VGPRs/AGPRs.
// TAGGED-WORD BROADCAST: h published as 8B words {data, tag=t+1} via
// fire-and-forget sc0sc1 stores; consumers retry-load until tags match.
// R12 lesson: B3 is LOAD-BEARING for performance -- it aligns spin-start
// with publish-completion (first retry then succeeds). Early spinning
// floods the LLC and adds retry quantization (R12: +2.6ms). Structure is
// R11's; deltas: 4 indep MFMA acc chains; trace/prefetch moved after B3
// (overlaps staging, releases B3 earlier).
__global__ __launch_bounds__(384, 2) void scan_kernel(
    const ushort* __restrict__ GI, const float* __restrict__ G,
    const float* __restrict__ w_hh, const float* __restrict__ b_hh,
    ushort* __restrict__ hb, float* __restrict__ out)
{
  __shared__ ushort hl[16 * 1024];   // staged h, M=16 rows (rows 4-15 zero), swizzled
  __shared__ float ghx[4 * 96];      // gh exchange [b][gate*32+e_local]
  const int tid = threadIdx.x;
  const int wgid = blockIdx.x;       // 0..255
  const int Gp = wgid >> 5;          // group 0..7
  const int c  = wgid & 31;          // CU within group
  const int wid = tid >> 6, lane = tid & 63;
  char* hbb = (char*)hb;

  const int gateW = wid >> 1;            // 0..2 (r,z,n)
  const int ehW = (wid & 1) * 16;        // e sub-tile within the 32

  // one-time: this wave's 32 w_hh B-fragments -> registers (bf16).
  bf16x8 bfr[32];
  {
    const float* wsrc = w_hh
        + ((size_t)(gateW * 1024 + c * 32 + ehW + (lane & 15))) * 1024
        + (lane >> 4) * 8;
#pragma unroll
    for (int kk = 0; kk < 32; ++kk) {
      float4 f0 = *(const float4*)(wsrc + kk * 32);
      float4 f1 = *(const float4*)(wsrc + kk * 32 + 4);
      union { ushort u[8]; bf16x8 v; } p;
      p.u[0]=f2bf(f0.x); p.u[1]=f2bf(f0.y); p.u[2]=f2bf(f0.z); p.u[3]=f2bf(f0.w);
      p.u[4]=f2bf(f1.x); p.u[5]=f2bf(f1.y); p.u[6]=f2bf(f1.z); p.u[7]=f2bf(f1.w);
      bfr[kk] = p.v;
    }
  }

  // zero pad rows 4..15 of the h stage (written once, swizzled layout)
  for (int idx = tid; idx < 1536; idx += 384) {
    int r = 4 + (idx >> 7), cc = idx & 127;
    int byte = (r * 2048 + cc * 16) ^ ((r & 7) << 4);
    uint4 z = {0u, 0u, 0u, 0u};
    *(uint4*)((char*)hl + byte) = z;
  }

  // A-frag read constants
  const int arow = lane & 15;            // batch row (0..3 valid)
  const int k0b = (lane >> 4) * 16;
  const int abase = arow * 2048, aswz = (arow & 7) << 4;
  const char* hlc = (const char*)hl;

  // combine-thread constants (tid<64): b=tid>>4 (4 rows), ep=tid&15 (e-pairs)
  const int b = tid >> 4;
  const int ep = tid & 15;
  const int brow = Gp * 4 + b;           // global batch row
  const int e2 = c * 32 + ep * 2;        // global e (pair base)
  float bhr0=0, bhr1=0, bhz0=0, bhz1=0, bhn0=0, bhn1=0;
  float h0r = 0.f, h1r = 0.f;            // own h pair in f32 registers
  unsigned int gir = 0, giz = 0, gin = 0; float gval = 0.f;
  if (tid < 64) {
    bhr0 = b_hh[e2];        bhr1 = b_hh[e2 + 1];
    bhz0 = b_hh[1024 + e2]; bhz1 = b_hh[1025 + e2];
    bhn0 = b_hh[2048 + e2]; bhn1 = b_hh[2049 + e2];
    // own h0 pair from the tagged buf0 (plain load; init ran on this stream)
    unsigned int v = *(const unsigned int*)(hbb + (size_t)Gp * 16384
                                            + (size_t)(b * 512 + c * 16 + ep) * 8);
    h0r = bf2f((ushort)(v & 0xffff)); h1r = bf2f((ushort)(v >> 16));
    const ushort* gp = GI + (size_t)brow * 3072 + e2;   // step-0 prefetch
    gir = *(const unsigned int*)(gp);
    giz = *(const unsigned int*)(gp + 1024);
    gin = *(const unsigned int*)(gp + 2048);
    gval = G[brow];
  }

  __syncthreads();

  for (int t = 0; t < 2048; ++t) {
    // stage h_t: retry-load 4x16B of tagged words until all tags == t,
    // then extract data dwords -> LDS swizzled. threads 0..255 cover 16KB.
    if (tid < 256) {
      const char* base = hbb + (size_t)(t & 1) * 131072 + (size_t)Gp * 16384
                         + (size_t)tid * 64;
      uint4 v0, v1, v2, v3;
      unsigned int tg = (unsigned int)t;
      for (;;) {
        asm volatile("global_load_dwordx4 %0, %1, off sc0 sc1"
                     : "=&v"(v0) : "v"(base) : "memory");
        asm volatile("global_load_dwordx4 %0, %1, off sc0 sc1"
                     : "=&v"(v1) : "v"(base + 16) : "memory");
        asm volatile("global_load_dwordx4 %0, %1, off sc0 sc1"
                     : "=&v"(v2) : "v"(base + 32) : "memory");
        asm volatile("global_load_dwordx4 %0, %1, off sc0 sc1"
                     : "=&v"(v3) : "v"(base + 48) : "memory");
        asm volatile("s_waitcnt vmcnt(0)" ::: "memory");
        if (v0.y == tg && v0.w == tg && v1.y == tg && v1.w == tg &&
            v2.y == tg && v2.w == tg && v3.y == tg && v3.w == tg) break;
        __builtin_amdgcn_s_sleep(1);
      }
      __builtin_amdgcn_sched_barrier(0);
      int r = tid >> 6, colb = (tid & 63) * 32, swz = (r & 7) << 4;
      uint4 da; da.x = v0.x; da.y = v0.z; da.z = v1.x; da.w = v1.z;
      uint4 db; db.x = v2.x; db.y = v2.z; db.z = v3.x; db.w = v3.z;
      *(uint4*)((char*)hl + ((r * 2048 + colb) ^ swz)) = da;
      *(uint4*)((char*)hl + ((r * 2048 + colb + 16) ^ swz)) = db;
    }
    asm volatile("s_waitcnt lgkmcnt(0)\n\ts_barrier" ::: "memory");   // B1 (LDS)
    __builtin_amdgcn_sched_barrier(0);

    // gh tile: M=4(in 16) x N=16 x K=1024 per wave; 4 indep acc chains
    f32x4 acc0 = {0.f,0.f,0.f,0.f}, acc1 = {0.f,0.f,0.f,0.f};
    f32x4 acc2 = {0.f,0.f,0.f,0.f}, acc3 = {0.f,0.f,0.f,0.f};
#pragma unroll
    for (int kk = 0; kk < 32; kk += 4) {
      int ka = kk * 64 + k0b;
      bf16x8 a0 = *(const bf16x8*)(hlc + abase + ((ka) ^ aswz));
      bf16x8 a1 = *(const bf16x8*)(hlc + abase + ((ka + 64) ^ aswz));
      bf16x8 a2 = *(const bf16x8*)(hlc + abase + ((ka + 128) ^ aswz));
      bf16x8 a3 = *(const bf16x8*)(hlc + abase + ((ka + 192) ^ aswz));
      acc0 = __builtin_amdgcn_mfma_f32_16x16x32_bf16(a0, bfr[kk],     acc0, 0, 0, 0);
      acc1 = __builtin_amdgcn_mfma_f32_16x16x32_bf16(a1, bfr[kk + 1], acc1, 0, 0, 0);
      acc2 = __builtin_amdgcn_mfma_f32_16x16x32_bf16(a2, bfr[kk + 2], acc2, 0, 0, 0);
      acc3 = __builtin_amdgcn_mfma_f32_16x16x32_bf16(a3, bfr[kk + 3], acc3, 0, 0, 0);
    }
    // D rows 0-3 (the real batch rows) live in lanes 0-15, reg j = row
    if (lane < 16) {
      f32x4 s = (acc0 + acc1) + (acc2 + acc3);
#pragma unroll
      for (int j = 0; j < 4; ++j)
        ghx[j * 96 + gateW * 32 + ehW + lane] = s[j];
    }
    asm volatile("s_waitcnt lgkmcnt(0)\n\ts_barrier" ::: "memory");   // B2 (LDS)
    __builtin_amdgcn_sched_barrier(0);

    // local combine (wave 0); publish h_{t+1} as tagged words (fire-and-forget)
    float u0 = 0.f, u1 = 0.f;
    if (tid < 64) {
      float hr0v = ghx[b * 96 + ep * 2],      hr1v = ghx[b * 96 + ep * 2 + 1];
      float hz0v = ghx[b * 96 + 32 + ep * 2], hz1v = ghx[b * 96 + 33 + ep * 2];
      float hn0v = ghx[b * 96 + 64 + ep * 2], hn1v = ghx[b * 96 + 65 + ep * 2];
      float r0 = sigf(bf2f((ushort)(gir & 0xffff)) + hr0v + bhr0);
      float r1 = sigf(bf2f((ushort)(gir >> 16))    + hr1v + bhr1);
      float z0 = sigf(bf2f((ushort)(giz & 0xffff)) + hz0v + bhz0);
      float z1 = sigf(bf2f((ushort)(giz >> 16))    + hz1v + bhz1);
      float n0 = 2.f * sigf(2.f * (bf2f((ushort)(gin & 0xffff)) + r0 * (hn0v + bhn0))) - 1.f;
      float n1 = 2.f * sigf(2.f * (bf2f((ushort)(gin >> 16))    + r1 * (hn1v + bhn1))) - 1.f;
      float nw0 = (1.f - z0) * n0 + z0 * h0r;
      float nw1 = (1.f - z1) * n1 + z1 * h1r;
      u0 = gval * nw0 + (1.f - gval) * h0r;
      u1 = gval * nw1 + (1.f - gval) * h1r;
      h0r = u0; h1r = u1;
      unsigned int hp = (unsigned int)f2bf(u0) | ((unsigned int)f2bf(u1) << 16);
      unsigned long long wd = ((unsigned long long)(unsigned int)(t + 1) << 32) | hp;
      char* haddr = hbb + (size_t)((t + 1) & 1) * 131072 + (size_t)Gp * 16384
                    + (size_t)(b * 512 + c * 16 + ep) * 8;
      asm volatile("global_store_dwordx2 %0, %1, off sc0 sc1"
                   :: "v"(haddr), "v"(wd) : "memory");
    }
    asm volatile("s_waitcnt lgkmcnt(0)\n\ts_barrier" ::: "memory");   // B3 (LDS)
    __builtin_amdgcn_sched_barrier(0);

    // after B3 (overlaps next staging): trace/stream + next-step prefetch
    if (tid < 64) {
      f32x2 uv; uv.x = u0; uv.y = u1;
      __builtin_nontemporal_store(uv,
          (f32x2*)(out + 786432 + ((size_t)brow * 2048 + t) * 1024 + e2));     // trace
      if (t >= 2024)
        __builtin_nontemporal_store(uv,
            (f32x2*)(out + ((size_t)brow * 24 + (t - 2024)) * 1024 + e2));     // stream
      int tn1 = t < 2047 ? t + 1 : 2047;
      const ushort* gp = GI + ((size_t)tn1 * 32 + brow) * 3072 + e2;
      gir = *(const unsigned int*)(gp);
      giz = *(const unsigned int*)(gp + 1024);
      gin = *(const unsigned int*)(gp + 2048);
      gval = G[tn1 * 32 + brow];
    }
  }
}

// ------------------------------------------------------------------ launch
extern "C" void kernel_launch(void* const* d_in, const int* in_sizes, int n_in,
                              void* d_out, int out_size, void* d_ws, size_t ws_size,
                              hipStream_t stream) {
  const float* x    = (const float*)d_in[0];
  const float* prev = (const float*)d_in[1];
  const float* gw1  = (const float*)d_in[2];
  const float* gb1  = (const float*)d_in[3];
  const float* gw2  = (const float*)d_in[4];
  const float* gb2  = (const float*)d_in[5];
  const float* wih  = (const float*)d_in[6];
  const float* whh  = (const float*)d_in[7];
  const float* bih  = (const float*)d_in[8];
  const float* bhh  = (const float*)d_in[9];
  float* out = (float*)d_out;

  char* ws = (char*)d_ws;
  ushort* xb    = (ushort*)(ws);                       // 134,217,728 B
  ushort* wbih  = (ushort*)(ws + 134217728);           //   6,291,456 B
  ushort* wb1   = (ushort*)(ws + 140509184);           //     524,288 B
  ushort* GI    = (ushort*)(ws + 141033472);           // 402,653,184 B
  ushort* GH1   = (ushort*)(ws + 543686656);           //  33,554,432 B
  float*  Gg    = (float*) (ws + 577241088);           //     262,144 B
  ushort* hb    = (ushort*)(ws + 577503232);           //     262,144 B (2 tagged bufs)
  // total 577,765,376 B (~551 MiB) of d_ws

  f32_to_bf16_k<<<32768, 256, 0, stream>>>(x, xb, 67108864);
  f32_to_bf16_k<<<1536, 256, 0, stream>>>(wih, wbih, 3145728);
  f32_to_bf16_k<<<128, 256, 0, stream>>>(gw1, wb1, 262144);
  gemm_bt<0><<<12288, 256, 0, stream>>>(xb, wbih, bih, GI, 65536, 3072, 1024);
  gemm_bt<1><<<1024, 256, 0, stream>>>(xb, wb1, gb1, GH1, 65536, 256, 1024);
  gate_reduce<<<16384, 256, 0, stream>>>(GH1, gw2, gb2, Gg);
  init_scan<<<64, 256, 0, stream>>>(prev, hb);
  scan_kernel<<<256, 384, 0, stream>>>(GI, Gg, whh, bhh, hb, out);
}

// Round 14
// 5909.568 us; speedup vs baseline: 1.4464x; 1.0995x over previous
//
#include <hip/hip_runtime.h>
#include <hip/hip_bf16.h>
#include <math.h>

// ConsciousnessStream: B=32, T=2048, E=1024, S=24
// out = [stream (32*24*1024 f32)] [trace (32*2048*1024 f32)]
// R14 = byte-exact revert to R11 (best measured: scan 5.31 ms, total 5.92 ms).
// R12/R13 lesson: wave 0's VMEM queue between publish and first tag-check is
// part of the rendezvous critical path -- trace/prefetch must be issued
// BEFORE B3 so their flight hides under barrier-arrival skew.

typedef __attribute__((ext_vector_type(4))) float f32x4;
typedef __attribute__((ext_vector_type(2))) float f32x2;
typedef __attribute__((ext_vector_type(8))) short bf16x8;

__device__ __forceinline__ ushort f2bf(float f) {
  unsigned int x = __float_as_uint(f);
  x += 0x7fffu + ((x >> 16) & 1u);   // RNE (finite data, no NaN handling)
  return (ushort)(x >> 16);
}
__device__ __forceinline__ float bf2f(ushort u) {
  return __uint_as_float(((unsigned int)u) << 16);
}
__device__ __forceinline__ float sigf(float x) {
  return 1.0f / (1.0f + __expf(-x));
}
__device__ __forceinline__ void gload_lds16(const void* g, void* l) {
  __builtin_amdgcn_global_load_lds(
      (const __attribute__((address_space(1))) unsigned int*)g,
      (__attribute__((address_space(3))) unsigned int*)l, 16, 0, 0);
}

// ---------------------------------------------------------------- converts
__global__ __launch_bounds__(256) void f32_to_bf16_k(const float* __restrict__ in,
                                                     ushort* __restrict__ out, int n) {
  int i = (blockIdx.x * 256 + threadIdx.x) * 8;
  if (i >= n) return;
  float4 a = *(const float4*)(in + i);
  float4 c = *(const float4*)(in + i + 4);
  union { ushort u[8]; uint4 v; } p;
  p.u[0]=f2bf(a.x); p.u[1]=f2bf(a.y); p.u[2]=f2bf(a.z); p.u[3]=f2bf(a.w);
  p.u[4]=f2bf(c.x); p.u[5]=f2bf(c.y); p.u[6]=f2bf(c.z); p.u[7]=f2bf(c.w);
  *(uint4*)(out + i) = p.v;
}

// ------------------------------------------------- bf16 GEMM, Bt = [N][K]
// EPI=0: C = bf16(acc + bias[col]) stored at GI[(t*32+b)*3072+col], m=b*2048+t
// EPI=1: C = bf16(gelu(acc + bias[col])) stored row-major [m][256]
template<int EPI>
__global__ __launch_bounds__(256) void gemm_bt(
    const ushort* __restrict__ A, const ushort* __restrict__ Bt,
    const float* __restrict__ bias, ushort* __restrict__ C,
    int M, int N, int K)
{
  __shared__ ushort lA[128 * 32];
  __shared__ ushort lB[128 * 32];
  const int tid = threadIdx.x;
  const int lane = tid & 63, wid = tid >> 6;
  const int tiles_n = N >> 7;
  const int tm = blockIdx.x / tiles_n, tn = blockIdx.x % tiles_n;
  const int wr = wid >> 1, wc = wid & 1;

  const f32x4 zero = {0.f, 0.f, 0.f, 0.f};
  f32x4 acc[4][4];
#pragma unroll
  for (int i = 0; i < 4; ++i)
#pragma unroll
    for (int n = 0; n < 4; ++n) acc[i][n] = zero;

  const ushort* gA = A + (size_t)tm * 128 * K;
  const ushort* gB = Bt + (size_t)tn * 128 * K;
  const int k0 = (lane >> 4) * 8;

  for (int kt = 0; kt < K; kt += 32) {
    __syncthreads();
#pragma unroll
    for (int i = 0; i < 2; ++i) {
      int chunk = i * 256 + tid;          // 512 16B-chunks per 128x32 tile
      int rr = chunk >> 2, cc = chunk & 3;
      gload_lds16(gA + (size_t)rr * K + kt + cc * 8, lA + chunk * 8);
      gload_lds16(gB + (size_t)rr * K + kt + cc * 8, lB + chunk * 8);
    }
    __syncthreads();
    bf16x8 af[4], bfv[4];
#pragma unroll
    for (int i = 0; i < 4; ++i)
      af[i] = *(const bf16x8*)(lA + (wr * 64 + i * 16 + (lane & 15)) * 32 + k0);
#pragma unroll
    for (int n = 0; n < 4; ++n)
      bfv[n] = *(const bf16x8*)(lB + (wc * 64 + n * 16 + (lane & 15)) * 32 + k0);
#pragma unroll
    for (int i = 0; i < 4; ++i)
#pragma unroll
      for (int n = 0; n < 4; ++n)
        acc[i][n] = __builtin_amdgcn_mfma_f32_16x16x32_bf16(af[i], bfv[n], acc[i][n], 0, 0, 0);
  }

#pragma unroll
  for (int i = 0; i < 4; ++i) {
#pragma unroll
    for (int n = 0; n < 4; ++n) {
#pragma unroll
      for (int j = 0; j < 4; ++j) {
        int m = tm * 128 + wr * 64 + i * 16 + (lane >> 4) * 4 + j;
        int col = tn * 128 + wc * 64 + n * 16 + (lane & 15);
        float v = acc[i][n][j] + bias[col];
        if (EPI == 0) {
          int tt = m & 2047, bb = m >> 11;
          C[(size_t)(tt * 32 + bb) * 3072 + col] = f2bf(v);
        } else {
          float gl = 0.5f * v * (1.0f + erff(v * 0.70710678f));
          C[(size_t)m * 256 + col] = f2bf(gl);
        }
      }
    }
  }
}

// -------------------------------------------- gate reduce: g = sig(GH1.w2+b2)
__global__ __launch_bounds__(256) void gate_reduce(
    const ushort* __restrict__ GH1, const float* __restrict__ w2,
    const float* __restrict__ b2, float* __restrict__ G)
{
  int row = blockIdx.x * 4 + (threadIdx.x >> 6);  // m = b*2048 + t
  int lane = threadIdx.x & 63;
  const ushort* p = GH1 + (size_t)row * 256 + lane * 4;
  ushort4 h4 = *(const ushort4*)p;
  float4 w4 = *(const float4*)(w2 + lane * 4);
  float s = bf2f(h4.x) * w4.x + bf2f(h4.y) * w4.y + bf2f(h4.z) * w4.z + bf2f(h4.w) * w4.w;
#pragma unroll
  for (int o = 32; o > 0; o >>= 1) s += __shfl_down(s, o);
  if (lane == 0) {
    G[(row & 2047) * 32 + (row >> 11)] = sigf(s + b2[0]);
  }
}

// ------------------------------------------------------------------- init
// Tagged h ring: 2 bufs x 8 groups x 2048 words x 8B.
// word = {lo32: 2xbf16 data, hi32: tag}. buf0 <- h0 with tag 0;
// buf1 <- tag 0xFFFFFFFF (clears stale tags from previous graph replays).
__global__ __launch_bounds__(256) void init_scan(const float* __restrict__ prev,
                                                 ushort* __restrict__ hb)
{
  int gid = blockIdx.x * 256 + threadIdx.x;   // grid 64*256 = 16384 words
  if (gid >= 16384) return;
  int Gp = gid >> 11, idx = gid & 2047;
  int b = idx >> 9, p = idx & 511;
  int brow = Gp * 4 + b;
  const float* src = prev + ((size_t)brow * 24 + 23) * 1024 + p * 2;
  unsigned int data = (unsigned int)f2bf(src[0]) | ((unsigned int)f2bf(src[1]) << 16);
  char* base = (char*)hb;
  *(unsigned long long*)(base + (size_t)Gp * 16384 + (size_t)idx * 8) =
      (unsigned long long)data;                                   // tag 0
  *(unsigned long long*)(base + 131072 + (size_t)Gp * 16384 + (size_t)idx * 8) =
      0xFFFFFFFF00000000ULL;                                      // invalid tag
}

// ------------------------------------------------------- persistent scan
// BATCH-GROUP decomposition: 8 independent groups x 32 WGs (grid 256, 1/CU).
// Group Gp owns batch rows 4Gp..4Gp+3; WG c owns h-outputs e in
// [c*32, c*32+32) with the matching 96 w_hh rows in VGPRs/AGPRs.
// TAGGED-WORD BROADCAST: h published as 8B words {data, tag=t+1} via
// fire-and-forget sc0sc1 stores; consumers retry-load until tags match.
// All waves stage (spin-start aligned with publish via B3); combine in wave0
// issues publish THEN trace/prefetch BEFORE B3 so their flight hides under
// barrier skew and the next tag-check's vmcnt(0) sees only staging loads.
__global__ __launch_bounds__(384, 2) void scan_kernel(
    const ushort* __restrict__ GI, const float* __restrict__ G,
    const float* __restrict__ w_hh, const float* __restrict__ b_hh,
    ushort* __restrict__ hb, float* __restrict__ out)
{
  __shared__ ushort hl[16 * 1024];   // staged h, M=16 rows (rows 4-15 zero), swizzled
  __shared__ float ghx[4 * 96];      // gh exchange [b][gate*32+e_local]
  const int tid = threadIdx.x;
  const int wgid = blockIdx.x;       // 0..255
  const int Gp = wgid >> 5;          // group 0..7
  const int c  = wgid & 31;          // CU within group
  const int wid = tid >> 6, lane = tid & 63;
  char* hbb = (char*)hb;

  const int gateW = wid >> 1;            // 0..2 (r,z,n)
  const int ehW = (wid & 1) * 16;        // e sub-tile within the 32

  // one-time: this wave's 32 w_hh B-fragments -> registers (bf16).
  bf16x8 bfr[32];
  {
    const float* wsrc = w_hh
        + ((size_t)(gateW * 1024 + c * 32 + ehW + (lane & 15))) * 1024
        + (lane >> 4) * 8;
#pragma unroll
    for (int kk = 0; kk < 32; ++kk) {
      float4 f0 = *(const float4*)(wsrc + kk * 32);
      float4 f1 = *(const float4*)(wsrc + kk * 32 + 4);
      union { ushort u[8]; bf16x8 v; } p;
      p.u[0]=f2bf(f0.x); p.u[1]=f2bf(f0.y); p.u[2]=f2bf(f0.z); p.u[3]=f2bf(f0.w);
      p.u[4]=f2bf(f1.x); p.u[5]=f2bf(f1.y); p.u[6]=f2bf(f1.z); p.u[7]=f2bf(f1.w);
      bfr[kk] = p.v;
    }
  }

  // zero pad rows 4..15 of the h stage (written once, swizzled layout)
  for (int idx = tid; idx < 1536; idx += 384) {
    int r = 4 + (idx >> 7), cc = idx & 127;
    int byte = (r * 2048 + cc * 16) ^ ((r & 7) << 4);
    uint4 z = {0u, 0u, 0u, 0u};
    *(uint4*)((char*)hl + byte) = z;
  }

  // A-frag read constants
  const int arow = lane & 15;            // batch row (0..3 valid)
  const int k0b = (lane >> 4) * 16;
  const int abase = arow * 2048, aswz = (arow & 7) << 4;
  const char* hlc = (const char*)hl;

  // combine-thread constants (tid<64): b=tid>>4 (4 rows), ep=tid&15 (e-pairs)
  const int b = tid >> 4;
  const int ep = tid & 15;
  const int brow = Gp * 4 + b;           // global batch row
  const int e2 = c * 32 + ep * 2;        // global e (pair base)
  float bhr0=0, bhr1=0, bhz0=0, bhz1=0, bhn0=0, bhn1=0;
  float h0r = 0.f, h1r = 0.f;            // own h pair in f32 registers
  unsigned int gir = 0, giz = 0, gin = 0; float gval = 0.f;
  if (tid < 64) {
    bhr0 = b_hh[e2];        bhr1 = b_hh[e2 + 1];
    bhz0 = b_hh[1024 + e2]; bhz1 = b_hh[1025 + e2];
    bhn0 = b_hh[2048 + e2]; bhn1 = b_hh[2049 + e2];
    // own h0 pair from the tagged buf0 (plain load; init ran on this stream)
    unsigned int v = *(const unsigned int*)(hbb + (size_t)Gp * 16384
                                            + (size_t)(b * 512 + c * 16 + ep) * 8);
    h0r = bf2f((ushort)(v & 0xffff)); h1r = bf2f((ushort)(v >> 16));
    const ushort* gp = GI + (size_t)brow * 3072 + e2;   // step-0 prefetch
    gir = *(const unsigned int*)(gp);
    giz = *(const unsigned int*)(gp + 1024);
    gin = *(const unsigned int*)(gp + 2048);
    gval = G[brow];
  }

  __syncthreads();

  for (int t = 0; t < 2048; ++t) {
    // stage h_t: retry-load 4x16B of tagged words until all tags == t,
    // then extract data dwords -> LDS swizzled. threads 0..255 cover 16KB.
    if (tid < 256) {
      const char* base = hbb + (size_t)(t & 1) * 131072 + (size_t)Gp * 16384
                         + (size_t)tid * 64;
      uint4 v0, v1, v2, v3;
      unsigned int tg = (unsigned int)t;
      for (;;) {
        asm volatile("global_load_dwordx4 %0, %1, off sc0 sc1"
                     : "=&v"(v0) : "v"(base) : "memory");
        asm volatile("global_load_dwordx4 %0, %1, off sc0 sc1"
                     : "=&v"(v1) : "v"(base + 16) : "memory");
        asm volatile("global_load_dwordx4 %0, %1, off sc0 sc1"
                     : "=&v"(v2) : "v"(base + 32) : "memory");
        asm volatile("global_load_dwordx4 %0, %1, off sc0 sc1"
                     : "=&v"(v3) : "v"(base + 48) : "memory");
        asm volatile("s_waitcnt vmcnt(0)" ::: "memory");
        if (v0.y == tg && v0.w == tg && v1.y == tg && v1.w == tg &&
            v2.y == tg && v2.w == tg && v3.y == tg && v3.w == tg) break;
        __builtin_amdgcn_s_sleep(1);
      }
      __builtin_amdgcn_sched_barrier(0);
      int r = tid >> 6, colb = (tid & 63) * 32, swz = (r & 7) << 4;
      uint4 da; da.x = v0.x; da.y = v0.z; da.z = v1.x; da.w = v1.z;
      uint4 db; db.x = v2.x; db.y = v2.z; db.z = v3.x; db.w = v3.z;
      *(uint4*)((char*)hl + ((r * 2048 + colb) ^ swz)) = da;
      *(uint4*)((char*)hl + ((r * 2048 + colb + 16) ^ swz)) = db;
    }
    asm volatile("s_waitcnt lgkmcnt(0)\n\ts_barrier" ::: "memory");   // B1 (LDS)
    __builtin_amdgcn_sched_barrier(0);

    // gh tile: M=4(in 16) x N=16 x K=1024 per wave; B stationary in VGPRs
    f32x4 acc0 = {0.f,0.f,0.f,0.f}, acc1 = {0.f,0.f,0.f,0.f};
#pragma unroll
    for (int kk = 0; kk < 32; kk += 2) {
      int ka = kk * 64 + k0b;
      bf16x8 a0 = *(const bf16x8*)(hlc + abase + ((ka) ^ aswz));
      bf16x8 a1 = *(const bf16x8*)(hlc + abase + ((ka + 64) ^ aswz));
      acc0 = __builtin_amdgcn_mfma_f32_16x16x32_bf16(a0, bfr[kk],     acc0, 0, 0, 0);
      acc1 = __builtin_amdgcn_mfma_f32_16x16x32_bf16(a1, bfr[kk + 1], acc1, 0, 0, 0);
    }
    // D rows 0-3 (the real batch rows) live in lanes 0-15, reg j = row
    if (lane < 16) {
      f32x4 s = acc0 + acc1;
#pragma unroll
      for (int j = 0; j < 4; ++j)
        ghx[j * 96 + gateW * 32 + ehW + lane] = s[j];
    }
    asm volatile("s_waitcnt lgkmcnt(0)\n\ts_barrier" ::: "memory");   // B2 (LDS)
    __builtin_amdgcn_sched_barrier(0);

    // local combine (wave 0); publish h_{t+1} as tagged words, then trace +
    // next-step prefetch -- all issued BEFORE B3 (flight hides under skew).
    if (tid < 64) {
      float hr0v = ghx[b * 96 + ep * 2],      hr1v = ghx[b * 96 + ep * 2 + 1];
      float hz0v = ghx[b * 96 + 32 + ep * 2], hz1v = ghx[b * 96 + 33 + ep * 2];
      float hn0v = ghx[b * 96 + 64 + ep * 2], hn1v = ghx[b * 96 + 65 + ep * 2];
      float r0 = sigf(bf2f((ushort)(gir & 0xffff)) + hr0v + bhr0);
      float r1 = sigf(bf2f((ushort)(gir >> 16))    + hr1v + bhr1);
      float z0 = sigf(bf2f((ushort)(giz & 0xffff)) + hz0v + bhz0);
      float z1 = sigf(bf2f((ushort)(giz >> 16))    + hz1v + bhz1);
      float n0 = 2.f * sigf(2.f * (bf2f((ushort)(gin & 0xffff)) + r0 * (hn0v + bhn0))) - 1.f;
      float n1 = 2.f * sigf(2.f * (bf2f((ushort)(gin >> 16))    + r1 * (hn1v + bhn1))) - 1.f;
      float nw0 = (1.f - z0) * n0 + z0 * h0r;
      float nw1 = (1.f - z1) * n1 + z1 * h1r;
      float u0 = gval * nw0 + (1.f - gval) * h0r;
      float u1 = gval * nw1 + (1.f - gval) * h1r;
      h0r = u0; h1r = u1;
      unsigned int hp = (unsigned int)f2bf(u0) | ((unsigned int)f2bf(u1) << 16);
      unsigned long long wd = ((unsigned long long)(unsigned int)(t + 1) << 32) | hp;
      char* haddr = hbb + (size_t)((t + 1) & 1) * 131072 + (size_t)Gp * 16384
                    + (size_t)(b * 512 + c * 16 + ep) * 8;
      asm volatile("global_store_dwordx2 %0, %1, off sc0 sc1"
                   :: "v"(haddr), "v"(wd) : "memory");
      // off the publication path: trace/stream + next-step prefetch
      f32x2 uv; uv.x = u0; uv.y = u1;
      __builtin_nontemporal_store(uv,
          (f32x2*)(out + 786432 + ((size_t)brow * 2048 + t) * 1024 + e2));     // trace
      if (t >= 2024)
        __builtin_nontemporal_store(uv,
            (f32x2*)(out + ((size_t)brow * 24 + (t - 2024)) * 1024 + e2));     // stream
      int tn1 = t < 2047 ? t + 1 : 2047;
      const ushort* gp = GI + ((size_t)tn1 * 32 + brow) * 3072 + e2;
      gir = *(const unsigned int*)(gp);
      giz = *(const unsigned int*)(gp + 1024);
      gin = *(const unsigned int*)(gp + 2048);
      gval = G[tn1 * 32 + brow];
    }
    asm volatile("s_waitcnt lgkmcnt(0)\n\ts_barrier" ::: "memory");   // B3 (LDS)
    __builtin_amdgcn_sched_barrier(0);
  }
}

// ------------------------------------------------------------------ launch
extern "C" void kernel_launch(void* const* d_in, const int* in_sizes, int n_in,
                              void* d_out, int out_size, void* d_ws, size_t ws_size,
                              hipStream_t stream) {
  const float* x    = (const float*)d_in[0];
  const float* prev = (const float*)d_in[1];
  const float* gw1  = (const float*)d_in[2];
  const float* gb1  = (const float*)d_in[3];
  const float* gw2  = (const float*)d_in[4];
  const float* gb2  = (const float*)d_in[5];
  const float* wih  = (const float*)d_in[6];
  const float* whh  = (const float*)d_in[7];
  const float* bih  = (const float*)d_in[8];
  const float* bhh  = (const float*)d_in[9];
  float* out = (float*)d_out;

  char* ws = (char*)d_ws;
  ushort* xb    = (ushort*)(ws);                       // 134,217,728 B
  ushort* wbih  = (ushort*)(ws + 134217728);           //   6,291,456 B
  ushort* wb1   = (ushort*)(ws + 140509184);           //     524,288 B
  ushort* GI    = (ushort*)(ws + 141033472);           // 402,653,184 B
  ushort* GH1   = (ushort*)(ws + 543686656);           //  33,554,432 B
  float*  Gg    = (float*) (ws + 577241088);           //     262,144 B
  ushort* hb    = (ushort*)(ws + 577503232);           //     262,144 B (2 tagged bufs)
  // total 577,765,376 B (~551 MiB) of d_ws

  f32_to_bf16_k<<<32768, 256, 0, stream>>>(x, xb, 67108864);
  f32_to_bf16_k<<<1536, 256, 0, stream>>>(wih, wbih, 3145728);
  f32_to_bf16_k<<<128, 256, 0, stream>>>(gw1, wb1, 262144);
  gemm_bt<0><<<12288, 256, 0, stream>>>(xb, wbih, bih, GI, 65536, 3072, 1024);
  gemm_bt<1><<<1024, 256, 0, stream>>>(xb, wb1, gb1, GH1, 65536, 256, 1024);
  gate_reduce<<<16384, 256, 0, stream>>>(GH1, gw2, gb2, Gg);
  init_scan<<<64, 256, 0, stream>>>(prev, hb);
  scan_kernel<<<256, 384, 0, stream>>>(GI, Gg, whh, bhh, hb, out);
}